// Round 15
// baseline (217.641 us; speedup 1.0000x reference)
//
#include <hip/hip_runtime.h>
#include <hip/hip_bf16.h>
#include <math.h>

#define NEG_SLOPE 0.2f

typedef __attribute__((ext_vector_type(8))) short short8v;
typedef __attribute__((ext_vector_type(4))) float f32x4;

// ---------------- prep: zero count8/scan-state + pack B fragments ----------------
__global__ __launch_bounds__(256) void gat_prep(
    const float* __restrict__ W, const float* __restrict__ srcA,
    const float* __restrict__ dstA, ushort* __restrict__ wbf,
    int* __restrict__ count8, int cn,
    unsigned int* __restrict__ state, int* __restrict__ ticket)
{
  int gtid = blockIdx.x * 256 + threadIdx.x;
  for (int i = gtid; i < cn; i += gridDim.x * 256)
    count8[i] = 0;
  if (gtid < 256) state[gtid] = 0;
  if (gtid == 0) *ticket = 0;

  if (gtid >= 36 * 64) return;
  int frag = gtid >> 6, lane = gtid & 63;
  int nt = frag >> 2, ks = frag & 3;
  int kbase = ks * 32 + (lane >> 4) * 8;
  ushort v[8];
  if (nt < 8) {
    int r = nt * 16 + (lane & 15);   // output col n -> W row
#pragma unroll
    for (int j = 0; j < 8; ++j)
      v[j] = __bfloat16_as_ushort(__float2bfloat16(W[(size_t)r * 128 + kbase + j]));
  } else {
    int n = lane & 15;
    int hd = n & 7;
    const float* av = (n < 8) ? srcA : dstA;
#pragma unroll
    for (int j = 0; j < 8; ++j) {
      float acc = 0.f;
      int k = kbase + j;
      for (int d = 0; d < 16; ++d)
        acc += W[(size_t)(hd * 16 + d) * 128 + k] * av[hd * 16 + d];
      v[j] = __bfloat16_as_ushort(__float2bfloat16(acc));
    }
  }
  ushort* dst = wbf + ((size_t)frag * 64 + lane) * 8;
#pragma unroll
  for (int j = 0; j < 8; ++j) dst[j] = v[j];
}

// ---------------- shared GEMM chunk body (one 64-row chunk per block) ----------
__device__ __forceinline__ void gemm_chunk_body(
    const float* __restrict__ x, const ushort* __restrict__ wbf,
    ushort* __restrict__ hb, float* __restrict__ s, float* __restrict__ dv,
    int N, int chunk)
{
  const int wave = threadIdx.x >> 6, lane = threadIdx.x & 63;
  const int lrow = lane & 15, lkg = lane >> 4;

  short8v b[36];
  const short8v* wv = (const short8v*)wbf;
#pragma unroll
  for (int f = 0; f < 36; ++f) b[f] = wv[(size_t)f * 64 + lane];

  const int r0 = chunk * 64 + wave * 16;
  int arow = r0 + lrow; if (arow > N - 1) arow = N - 1;
  const float* xr = x + (size_t)arow * 128 + lkg * 8;

  f32x4 acc[9];
#pragma unroll
  for (int t = 0; t < 9; ++t) acc[t] = (f32x4){0.f, 0.f, 0.f, 0.f};

#pragma unroll
  for (int ks = 0; ks < 4; ++ks) {
    float4 x0 = *(const float4*)(xr + ks * 32);
    float4 x1 = *(const float4*)(xr + ks * 32 + 4);
    short8v a;
    a[0] = (short)__bfloat16_as_ushort(__float2bfloat16(x0.x));
    a[1] = (short)__bfloat16_as_ushort(__float2bfloat16(x0.y));
    a[2] = (short)__bfloat16_as_ushort(__float2bfloat16(x0.z));
    a[3] = (short)__bfloat16_as_ushort(__float2bfloat16(x0.w));
    a[4] = (short)__bfloat16_as_ushort(__float2bfloat16(x1.x));
    a[5] = (short)__bfloat16_as_ushort(__float2bfloat16(x1.y));
    a[6] = (short)__bfloat16_as_ushort(__float2bfloat16(x1.z));
    a[7] = (short)__bfloat16_as_ushort(__float2bfloat16(x1.w));
#pragma unroll
    for (int t = 0; t < 9; ++t)
      acc[t] = __builtin_amdgcn_mfma_f32_16x16x32_bf16(a, b[t * 4 + ks], acc[t], 0, 0, 0);
  }

  const int rbase = r0 + lkg * 4;  // C/D: row = (lane>>4)*4 + reg, col = lane&15
#pragma unroll
  for (int t = 0; t < 8; ++t) {
#pragma unroll
    for (int r = 0; r < 4; ++r) {
      int row = rbase + r;
      if (row < N)
        hb[(size_t)row * 128 + t * 16 + lrow] =
            __bfloat16_as_ushort(__float2bfloat16(acc[t][r]));
    }
  }
#pragma unroll
  for (int r = 0; r < 4; ++r) {
    int row = rbase + r;
    if (row < N) {
      if (lrow < 8) s[(size_t)row * 8 + lrow] = acc[8][r];
      else          dv[(size_t)row * 8 + (lrow - 8)] = acc[8][r];
    }
  }
}

// ---------------- D2: privatized histogram (blocks < nhist) + gemm chunks ----
__global__ __launch_bounds__(256, 2) void gat_hist_gemm(
    const float* __restrict__ x, const ushort* __restrict__ wbf,
    ushort* __restrict__ hb, float* __restrict__ s, float* __restrict__ dv,
    int N, int nchunks, int c0,
    const int* __restrict__ ei, int E, int* __restrict__ count8,
    int* __restrict__ rank, int userank, int nhist)
{
  if ((int)blockIdx.x >= nhist) {
    int chunk = c0 + (int)blockIdx.x - nhist;
    if (chunk < nchunks) gemm_chunk_body(x, wbf, hb, s, dv, N, chunk);
    return;
  }
  __shared__ int sh64;
  if (threadIdx.x == 0) sh64 = 1;
  __syncthreads();
  if (ei[2 * threadIdx.x + 1] != 0) sh64 = 0;  // int32 layout -> odd word != 0
  __syncthreads();
  const int is64 = sh64;
  const int k = (int)(blockIdx.x & 7u);
  int* cnt = count8 + (size_t)k * N;

  const int npairs = (E + 1) >> 1;
  const int pstride = nhist * 256;
  for (int p = (int)blockIdx.x * 256 + threadIdx.x; p < npairs; p += pstride) {
    int r0, r1;
    const int i1ok = (2 * p + 1) < E;
    if (is64) {
      int4 rr = *(const int4*)(ei + 4 * (size_t)p);
      r0 = rr.x; r1 = rr.z;
    } else {
      int2 rr = ((const int2*)ei)[p];
      r0 = rr.x; r1 = rr.y;
    }
    int old0 = atomicAdd(&cnt[r0], 1);
    int old1 = i1ok ? atomicAdd(&cnt[r1], 1) : 0;
    if (userank) {
      if (i1ok) ((int2*)rank)[p] = make_int2(old0 | (k << 28), old1 | (k << 28));
      else      rank[2 * p] = old0 | (k << 28);
    }
  }
}

// ---------------- D3: decoupled-lookback scan (blocks < nb) + gemm chunks ----
template<int NPRIV>
__global__ __launch_bounds__(256, 2) void gat_scan_gemm(
    const int* __restrict__ count8, int N, int nb,
    unsigned int* __restrict__ state, int* __restrict__ ticket,
    int* __restrict__ offsets, int* __restrict__ suboff,
    int* __restrict__ cursor, int total, int userank,
    const float* __restrict__ x, const ushort* __restrict__ wbf,
    ushort* __restrict__ hb, float* __restrict__ s, float* __restrict__ dv,
    int nchunks, int c0)
{
  if ((int)blockIdx.x >= nb) {
    int chunk = c0 + (int)blockIdx.x - nb;
    if (chunk < nchunks) gemm_chunk_body(x, wbf, hb, s, dv, N, chunk);
    return;
  }
  __shared__ int sbid;
  __shared__ int sm[256];
  __shared__ int sprefix;
  if (threadIdx.x == 0) sbid = atomicAdd(ticket, 1);
  __syncthreads();
  const int bid = sbid;
  const int base = bid * 1024 + threadIdx.x * 4;

  int c[4][NPRIV];
  int v[4];
  int tsum = 0;
#pragma unroll
  for (int j = 0; j < 4; ++j) {
    int idx = base + j;
    int cs = 0;
#pragma unroll
    for (int k = 0; k < NPRIV; ++k) {
      int cv = (idx < N) ? count8[(size_t)k * N + idx] : 0;
      c[j][k] = cv; cs += cv;
    }
    v[j] = (idx < N) ? cs : 0;       // no self-loop slot (agg handles self)
    tsum += v[j];
  }

  sm[threadIdx.x] = tsum;
  __syncthreads();
  int acc = tsum;
  for (int off = 1; off < 256; off <<= 1) {
    int other = (threadIdx.x >= off) ? sm[threadIdx.x - off] : 0;
    __syncthreads();
    acc += other;
    sm[threadIdx.x] = acc;
    __syncthreads();
  }
  const int blocktotal = sm[255];

  if (threadIdx.x == 0)
    __hip_atomic_store(&state[bid], (1u << 30) | (unsigned)blocktotal,
                       __ATOMIC_RELEASE, __HIP_MEMORY_SCOPE_AGENT);
  if (threadIdx.x < 64) {
    const int lane = threadIdx.x;
    int ex = 0;
    int j = bid - 1;
    while (j >= 0) {
      int idx = j - lane;
      unsigned d = (idx >= 0)
          ? __hip_atomic_load(&state[idx], __ATOMIC_ACQUIRE, __HIP_MEMORY_SCOPE_AGENT)
          : (2u << 30);
      unsigned st = d >> 30;
      unsigned long long m2 = __ballot(st == 2u);
      unsigned long long m0 = __ballot(st == 0u);
      int f2 = m2 ? ((int)__ffsll((long long)m2) - 1) : 64;
      int f0 = m0 ? ((int)__ffsll((long long)m0) - 1) : 64;
      if (f0 < f2) continue;
      int take = (lane < f2 || (lane == f2 && f2 < 64)) ? (int)(d & 0x3FFFFFFFu) : 0;
#pragma unroll
      for (int off = 1; off < 64; off <<= 1) take += __shfl_xor(take, off, 64);
      ex += take;
      if (f2 < 64) break;
      j -= 64;
    }
    if (lane == 0) {
      __hip_atomic_store(&state[bid], (2u << 30) | (unsigned)(ex + blocktotal),
                         __ATOMIC_RELEASE, __HIP_MEMORY_SCOPE_AGENT);
      sprefix = ex;
    }
  }
  __syncthreads();

  int e = sprefix + acc - tsum;
#pragma unroll
  for (int j = 0; j < 4; ++j) {
    int idx = base + j;
    if (idx < N) {
      offsets[idx] = e;
      int run = e;
#pragma unroll
      for (int k = 0; k < NPRIV; ++k) { suboff[(size_t)k * N + idx] = run; run += c[j][k]; }
      cursor[idx] = e;                // fallback-scatter cursor init
      e += v[j];
    }
  }
  if (bid == nb - 1 && threadIdx.x == 255) offsets[N] = total;
}

// ---------------- D4: atomic-free rank scatter (blocks < nsc) + gemm chunks ----
__global__ __launch_bounds__(256, 2) void gat_scatter_gemm(
    const int* __restrict__ ei, int E, int N,
    const int* __restrict__ suboff, const int* __restrict__ rank,
    int* __restrict__ scol,
    const float* __restrict__ x, const ushort* __restrict__ wbf,
    ushort* __restrict__ hb, float* __restrict__ s, float* __restrict__ dv,
    int nchunks, int c0, int nsc)
{
  if ((int)blockIdx.x >= nsc) {
    int chunk = c0 + (int)blockIdx.x - nsc;
    if (chunk < nchunks) gemm_chunk_body(x, wbf, hb, s, dv, N, chunk);
    return;
  }
  __shared__ int sh64;
  if (threadIdx.x == 0) sh64 = 1;
  __syncthreads();
  if (ei[2 * threadIdx.x + 1] != 0) sh64 = 0;
  __syncthreads();
  const int is64 = sh64;

  const int gid = (int)blockIdx.x * 256 + threadIdx.x;
  const int stride = nsc * 256;
  const int npairs = (E + 1) >> 1;
  for (int p = gid; p < npairs; p += stride) {
    int r0, r1, c0v, c1v;
    const int i1ok = (2 * p + 1) < E;
    if (is64) {
      int4 rr = *(const int4*)(ei + 4 * (size_t)p);
      int2 ca = *(const int2*)(ei + 2 * (size_t)E + 4 * (size_t)p);
      int2 cb = *(const int2*)(ei + 2 * (size_t)E + 4 * (size_t)p + 2);
      r0 = rr.x; r1 = rr.z; c0v = ca.x; c1v = cb.x;
    } else {
      int2 rr = ((const int2*)ei)[p];
      r0 = rr.x; r1 = rr.y;
      c0v = ei[E + 2 * p];
      c1v = i1ok ? ei[E + 2 * p + 1] : 0;
    }
    int2 pr = ((const int2*)rank)[p];
    int k0 = (int)(((unsigned)pr.x) >> 28);
    int pos0 = suboff[(size_t)k0 * N + r0] + (pr.x & 0x0FFFFFFF);
    scol[pos0] = c0v;
    if (i1ok) {
      int k1 = (int)(((unsigned)pr.y) >> 28);
      int pos1 = suboff[(size_t)k1 * N + r1] + (pr.y & 0x0FFFFFFF);
      scol[pos1] = c1v;
    }
  }
}

// ---------------- fallback: atomic-cursor scatter (if ws too small) ----------
__global__ __launch_bounds__(256) void gat_scatter(
    const int* __restrict__ ei, int E, int N,
    int* __restrict__ cursor, int* __restrict__ scol)
{
  __shared__ int sh64;
  if (threadIdx.x == 0) sh64 = 1;
  __syncthreads();
  if (ei[2 * threadIdx.x + 1] != 0) sh64 = 0;
  __syncthreads();
  const int is64 = sh64;

  int i = blockIdx.x * 256 + threadIdx.x;
  const int stride = gridDim.x * 256;
  for (; i < E; i += stride) {
    int r, c;
    if (is64) { r = ei[2 * i]; c = ei[2 * (E + i)]; }
    else      { r = ei[i];     c = ei[E + i]; }
    int pos = atomicAdd(&cursor[r], 1);
    scol[pos] = c;
  }
}

// ---------------- per-row softmax + SpMM, one wave per row ----------------
// Self-loop handled analytically — contribution masked to lane-group 0 only
// (all 4 groups load it, but only one may add it: the epilogue shfl reduce
// sums across groups, so unmasked it would count 4x — the R14 bug).
__global__ __launch_bounds__(256) void gat_agg(
    const uint* __restrict__ hb, const float* __restrict__ s, const float* __restrict__ dv,
    const int* __restrict__ offsets, const int* __restrict__ scol,
    float* __restrict__ out, int N)
{
  int wid = (int)((blockIdx.x * 256 + threadIdx.x) >> 6);
  int lane = threadIdx.x & 63;
  if (wid >= N) return;
  const int g = lane >> 4;          // edge slot within quad
  const int t = lane & 15;          // dims 8t..8t+7
  const int head = t >> 1;
  const int beg = __builtin_amdgcn_readfirstlane(offsets[wid]);
  const int end = __builtin_amdgcn_readfirstlane(offsets[wid + 1]);
  const float sl = s[wid * 8 + head];

  const char* hbp = (const char*)hb;
  const char* dvp = (const char*)dv;
  const uint hoff = (uint)t * 16u;
  const uint doff = (uint)head * 4u;

  // self-loop contribution (group 0 only — see comment above)
  float dls = *(const float*)(dvp + ((uint)wid * 32u + doff));
  uint4 hus = *(const uint4*)(hbp + ((uint)wid * 256u + hoff));
  float es = sl + dls;
  es = fmaxf(es, NEG_SLOPE * es);
  float ws = (g == 0) ? __expf(es) : 0.f;
  float z = ws;
  float a0 = ws * __uint_as_float(hus.x << 16);
  float a1 = ws * __uint_as_float(hus.x & 0xFFFF0000u);
  float a2 = ws * __uint_as_float(hus.y << 16);
  float a3 = ws * __uint_as_float(hus.y & 0xFFFF0000u);
  float a4 = ws * __uint_as_float(hus.z << 16);
  float a5 = ws * __uint_as_float(hus.z & 0xFFFF0000u);
  float a6 = ws * __uint_as_float(hus.w << 16);
  float a7 = ws * __uint_as_float(hus.w & 0xFFFF0000u);

  if (end > beg) {
    const int nq = (end - beg + 3) >> 2;
    const int lasti = end - 1;

    int iA = beg + g;       iA = iA < end ? iA : lasti;
    int iB = beg + 4 + g;   iB = iB < end ? iB : lasti;
    int iC = beg + 8 + g;   iC = iC < end ? iC : lasti;
    int cB = scol[iB];
    int cC = scol[iC];
    int cA = scol[iA];
    float dlA = *(const float*)(dvp + ((uint)cA * 32u + doff));
    uint4 huA = *(const uint4*)(hbp + ((uint)cA * 256u + hoff));
    float dlB = *(const float*)(dvp + ((uint)cB * 32u + doff));
    uint4 huB = *(const uint4*)(hbp + ((uint)cB * 256u + hoff));

    for (int j = 0; j < nq; ++j) {
      int iD = beg + 4 * (j + 3) + g; iD = iD < end ? iD : lasti;
      int cD = scol[iD];
      float dlC = *(const float*)(dvp + ((uint)cC * 32u + doff));
      uint4 huC = *(const uint4*)(hbp + ((uint)cC * 256u + hoff));

      float e = sl + dlA;
      e = fmaxf(e, NEG_SLOPE * e);
      float w = (beg + 4 * j + g < end) ? __expf(e) : 0.f;
      z += w;
      a0 = fmaf(w, __uint_as_float(huA.x << 16), a0);
      a1 = fmaf(w, __uint_as_float(huA.x & 0xFFFF0000u), a1);
      a2 = fmaf(w, __uint_as_float(huA.y << 16), a2);
      a3 = fmaf(w, __uint_as_float(huA.y & 0xFFFF0000u), a3);
      a4 = fmaf(w, __uint_as_float(huA.z << 16), a4);
      a5 = fmaf(w, __uint_as_float(huA.z & 0xFFFF0000u), a5);
      a6 = fmaf(w, __uint_as_float(huA.w << 16), a6);
      a7 = fmaf(w, __uint_as_float(huA.w & 0xFFFF0000u), a7);

      dlA = dlB; huA = huB;
      dlB = dlC; huB = huC;
      cC = cD;
    }
  }

  a0 += __shfl_xor(a0, 16, 64); a0 += __shfl_xor(a0, 32, 64);
  a1 += __shfl_xor(a1, 16, 64); a1 += __shfl_xor(a1, 32, 64);
  a2 += __shfl_xor(a2, 16, 64); a2 += __shfl_xor(a2, 32, 64);
  a3 += __shfl_xor(a3, 16, 64); a3 += __shfl_xor(a3, 32, 64);
  a4 += __shfl_xor(a4, 16, 64); a4 += __shfl_xor(a4, 32, 64);
  a5 += __shfl_xor(a5, 16, 64); a5 += __shfl_xor(a5, 32, 64);
  a6 += __shfl_xor(a6, 16, 64); a6 += __shfl_xor(a6, 32, 64);
  a7 += __shfl_xor(a7, 16, 64); a7 += __shfl_xor(a7, 32, 64);
  z  += __shfl_xor(z, 16, 64);  z  += __shfl_xor(z, 32, 64);

  float inv = 1.f / z;
  if (lane < 16) {
    float4* op = (float4*)(out + (size_t)wid * 128 + t * 8);
    op[0] = make_float4(a0 * inv, a1 * inv, a2 * inv, a3 * inv);
    op[1] = make_float4(a4 * inv, a5 * inv, a6 * inv, a7 * inv);
  }
}

extern "C" void kernel_launch(void* const* d_in, const int* in_sizes, int n_in,
                              void* d_out, int out_size, void* d_ws, size_t ws_size,
                              hipStream_t stream) {
  const float* x    = (const float*)d_in[0];
  const int*   ei   = (const int*)d_in[1];
  const float* W    = (const float*)d_in[2];
  const float* srcA = (const float*)d_in[3];
  const float* dstA = (const float*)d_in[4];
  float* out = (float*)d_out;
  const int N = in_sizes[0] / 128;
  const int E = in_sizes[1] / 2;

  auto need = [&](int npriv, int userank) -> size_t {
    size_t b = (size_t)N * 128 * 2;          // hbuf
    b += (size_t)N * 8 * 4 * 2;              // s, dv
    b += 36864;                              // wbf
    b += (size_t)npriv * N * 4;              // count8
    b += (size_t)(N + 1) * 4;                // offsets
    b += (size_t)npriv * N * 4;              // suboff
    b += (size_t)N * 4;                      // cursor
    b += 256 * 4 + 16;                       // state + ticket
    b += (size_t)E * 4;                      // scol
    if (userank) b += (size_t)(E + 1) * 4;   // rank (padded for pair store)
    return b;
  };
  int npriv = 8, userank = 1;
  if (need(8, 1) > ws_size) { npriv = 1; userank = 1; }
  if (need(1, 1) > ws_size) { npriv = 1; userank = 0; }

  ushort* hbuf = (ushort*)d_ws;                       // N*128 bf16
  float* s  = (float*)(hbuf + (size_t)N * 128);       // N*8
  float* dv = s + (size_t)N * 8;                      // N*8
  ushort* wbf = (ushort*)(dv + (size_t)N * 8);        // 36864 B
  int* count8  = (int*)((char*)wbf + 36864);          // npriv*N
  int* offsets = count8 + (size_t)npriv * N;          // N+1
  int* suboff  = offsets + (N + 1);                   // npriv*N
  int* cursor  = suboff + (size_t)npriv * N;          // N
  unsigned int* state = (unsigned int*)(cursor + N);  // 256
  int* ticket  = (int*)(state + 256);                 // 4 (padded)
  int* scol    = ticket + 4;                          // E
  int* rank    = scol + E;                            // E+1 (if userank)

  const int nchunks = (N + 63) / 64;
  const int nb = (N + 1023) / 1024;
  const int NHIST = 1024, NSC = 1024;
  // GEMM chunk split across the three mid-pipeline dispatches
  const int C1 = nchunks < 700 ? nchunks : 700;
  const int C2 = (C1 + 250) < nchunks ? (C1 + 250) : nchunks;
  const int g2 = C1, g3 = C2 - C1, g4 = nchunks - C2;

  gat_prep<<<2048, 256, 0, stream>>>(W, srcA, dstA, wbf, count8, npriv * N, state, ticket);
  gat_hist_gemm<<<NHIST + g2, 256, 0, stream>>>(x, wbf, hbuf, s, dv, N, nchunks, 0,
                                                ei, E, count8, rank, userank, NHIST);
  if (npriv == 8)
    gat_scan_gemm<8><<<nb + g3, 256, 0, stream>>>(count8, N, nb, state, ticket, offsets,
                                                  suboff, cursor, E, userank,
                                                  x, wbf, hbuf, s, dv, nchunks, C1);
  else
    gat_scan_gemm<1><<<nb + g3, 256, 0, stream>>>(count8, N, nb, state, ticket, offsets,
                                                  suboff, cursor, E, userank,
                                                  x, wbf, hbuf, s, dv, nchunks, C1);
  if (userank)
    gat_scatter_gemm<<<NSC + g4, 256, 0, stream>>>(ei, E, N, suboff, rank, scol,
                                                   x, wbf, hbuf, s, dv, nchunks, C2, NSC);
  else {
    gat_scatter_gemm<<<(g4 > 0 ? g4 : 1), 256, 0, stream>>>(ei, 0, N, suboff, rank, scol,
                                                   x, wbf, hbuf, s, dv, nchunks, C2, 0);
    gat_scatter<<<2048, 256, 0, stream>>>(ei, E, N, cursor, scol);
  }
  gat_agg<<<(N + 3) / 4, 256, 0, stream>>>((const uint*)hbuf, s, dv, offsets, scol, out, N);
}

// Round 16
// 211.753 us; speedup vs baseline: 1.0278x; 1.0278x over previous
//
#include <hip/hip_runtime.h>
#include <hip/hip_bf16.h>
#include <math.h>

#define NEG_SLOPE 0.2f

typedef __attribute__((ext_vector_type(8))) short short8v;
typedef __attribute__((ext_vector_type(4))) float f32x4;

// ---------------- prep: pack B fragments [W^T | Ps | Pd] (bf16) only ----------
__global__ __launch_bounds__(256) void gat_prep_wbf(
    const float* __restrict__ W, const float* __restrict__ srcA,
    const float* __restrict__ dstA, ushort* __restrict__ wbf)
{
  int gtid = blockIdx.x * 256 + threadIdx.x;
  if (gtid >= 36 * 64) return;
  int frag = gtid >> 6, lane = gtid & 63;
  int nt = frag >> 2, ks = frag & 3;
  int kbase = ks * 32 + (lane >> 4) * 8;
  ushort v[8];
  if (nt < 8) {
    int r = nt * 16 + (lane & 15);   // output col n -> W row
#pragma unroll
    for (int j = 0; j < 8; ++j)
      v[j] = __bfloat16_as_ushort(__float2bfloat16(W[(size_t)r * 128 + kbase + j]));
  } else {
    int n = lane & 15;
    int hd = n & 7;
    const float* av = (n < 8) ? srcA : dstA;
#pragma unroll
    for (int j = 0; j < 8; ++j) {
      float acc = 0.f;
      int k = kbase + j;
      for (int d = 0; d < 16; ++d)
        acc += W[(size_t)(hd * 16 + d) * 128 + k] * av[hd * 16 + d];
      v[j] = __bfloat16_as_ushort(__float2bfloat16(acc));
    }
  }
  ushort* dst = wbf + ((size_t)frag * 64 + lane) * 8;
#pragma unroll
  for (int j = 0; j < 8; ++j) dst[j] = v[j];
}

// ---------------- fused: MFMA GEMM (3/5 of blocks) + privatized histogram ----
__global__ __launch_bounds__(256, 2) void gat_gemm_hist(
    const float* __restrict__ x, const ushort* __restrict__ wbf,
    ushort* __restrict__ hb, float* __restrict__ s, float* __restrict__ dv,
    int N, int nchunks, int NG, int NH,
    const int* __restrict__ ei, int E, int* __restrict__ count8,
    int* __restrict__ rank, int userank)
{
  const int q = (int)blockIdx.x / 5;
  const int r5 = (int)blockIdx.x % 5;
  if (r5 < 3) {
    // ---- GEMM block (q*3 + r5) of NG; b[36] loaded once, chunk loop ----
    const int gemmId = q * 3 + r5;
    const int wave = threadIdx.x >> 6, lane = threadIdx.x & 63;
    const int lrow = lane & 15, lkg = lane >> 4;

    short8v b[36];
    const short8v* wv = (const short8v*)wbf;
#pragma unroll
    for (int f = 0; f < 36; ++f) b[f] = wv[(size_t)f * 64 + lane];

    for (int chunk = gemmId; chunk < nchunks; chunk += NG) {
      const int r0 = chunk * 64 + wave * 16;
      int arow = r0 + lrow; if (arow > N - 1) arow = N - 1;
      const float* xr = x + (size_t)arow * 128 + lkg * 8;

      f32x4 acc[9];
#pragma unroll
      for (int t = 0; t < 9; ++t) acc[t] = (f32x4){0.f, 0.f, 0.f, 0.f};

#pragma unroll
      for (int ks = 0; ks < 4; ++ks) {
        float4 x0 = *(const float4*)(xr + ks * 32);
        float4 x1 = *(const float4*)(xr + ks * 32 + 4);
        short8v a;
        a[0] = (short)__bfloat16_as_ushort(__float2bfloat16(x0.x));
        a[1] = (short)__bfloat16_as_ushort(__float2bfloat16(x0.y));
        a[2] = (short)__bfloat16_as_ushort(__float2bfloat16(x0.z));
        a[3] = (short)__bfloat16_as_ushort(__float2bfloat16(x0.w));
        a[4] = (short)__bfloat16_as_ushort(__float2bfloat16(x1.x));
        a[5] = (short)__bfloat16_as_ushort(__float2bfloat16(x1.y));
        a[6] = (short)__bfloat16_as_ushort(__float2bfloat16(x1.z));
        a[7] = (short)__bfloat16_as_ushort(__float2bfloat16(x1.w));
#pragma unroll
        for (int t = 0; t < 9; ++t)
          acc[t] = __builtin_amdgcn_mfma_f32_16x16x32_bf16(a, b[t * 4 + ks], acc[t], 0, 0, 0);
      }

      const int rbase = r0 + lkg * 4;  // C/D: row = (lane>>4)*4 + reg, col = lane&15
#pragma unroll
      for (int t = 0; t < 8; ++t) {
#pragma unroll
        for (int r = 0; r < 4; ++r) {
          int row = rbase + r;
          if (row < N)
            hb[(size_t)row * 128 + t * 16 + lrow] =
                __bfloat16_as_ushort(__float2bfloat16(acc[t][r]));
        }
      }
#pragma unroll
      for (int r = 0; r < 4; ++r) {
        int row = rbase + r;
        if (row < N) {
          if (lrow < 8) s[(size_t)row * 8 + lrow] = acc[8][r];
          else          dv[(size_t)row * 8 + (lrow - 8)] = acc[8][r];
        }
      }
    }
  } else {
    // ---- hist block (q*2 + r5-3) of NH; 2 edges/iter; copy k = blockIdx&7 ----
    __shared__ int sh64;
    if (threadIdx.x == 0) sh64 = 1;
    __syncthreads();
    if (ei[2 * threadIdx.x + 1] != 0) sh64 = 0;  // int32 layout -> odd word != 0
    __syncthreads();
    const int is64 = sh64;
    const int k = (int)(blockIdx.x & 7u);
    int* cnt = count8 + (size_t)k * N;

    const int histId = q * 2 + (r5 - 3);
    const int npairs = (E + 1) >> 1;
    const int pstride = NH * 256;
    for (int p = histId * 256 + threadIdx.x; p < npairs; p += pstride) {
      int r0, r1;
      const int i1ok = (2 * p + 1) < E;
      if (is64) {
        int4 rr = *(const int4*)(ei + 4 * (size_t)p);
        r0 = rr.x; r1 = rr.z;
      } else {
        int2 rr = ((const int2*)ei)[p];
        r0 = rr.x; r1 = rr.y;
      }
      int old0 = atomicAdd(&cnt[r0], 1);
      int old1 = i1ok ? atomicAdd(&cnt[r1], 1) : 0;
      if (userank) {
        if (i1ok) ((int2*)rank)[p] = make_int2(old0 | (k << 28), old1 | (k << 28));
        else      rank[2 * p] = old0 | (k << 28);
      }
    }
  }
}

// ---------------- decoupled-lookback scan over npriv copies (E-only) ----------
template<int NPRIV>
__global__ __launch_bounds__(256) void gat_scan(
    const int* __restrict__ count8, int N, int nb,
    unsigned int* __restrict__ state, int* __restrict__ ticket,
    int* __restrict__ offsets, int* __restrict__ suboff,
    int* __restrict__ cursor, int total)
{
  __shared__ int sbid;
  __shared__ int sm[256];
  __shared__ int sprefix;
  if (threadIdx.x == 0) sbid = atomicAdd(ticket, 1);
  __syncthreads();
  const int bid = sbid;
  const int base = bid * 1024 + threadIdx.x * 4;

  int c[4][NPRIV];
  int v[4];
  int tsum = 0;
#pragma unroll
  for (int j = 0; j < 4; ++j) {
    int idx = base + j;
    int cs = 0;
#pragma unroll
    for (int k = 0; k < NPRIV; ++k) {
      int cv = (idx < N) ? count8[(size_t)k * N + idx] : 0;
      c[j][k] = cv; cs += cv;
    }
    v[j] = (idx < N) ? cs : 0;       // no self-loop slot (agg handles self)
    tsum += v[j];
  }

  sm[threadIdx.x] = tsum;
  __syncthreads();
  int acc = tsum;
  for (int off = 1; off < 256; off <<= 1) {
    int other = (threadIdx.x >= off) ? sm[threadIdx.x - off] : 0;
    __syncthreads();
    acc += other;
    sm[threadIdx.x] = acc;
    __syncthreads();
  }
  const int blocktotal = sm[255];

  if (threadIdx.x == 0)
    __hip_atomic_store(&state[bid], (1u << 30) | (unsigned)blocktotal,
                       __ATOMIC_RELEASE, __HIP_MEMORY_SCOPE_AGENT);
  if (threadIdx.x < 64) {
    const int lane = threadIdx.x;
    int ex = 0;
    int j = bid - 1;
    while (j >= 0) {
      int idx = j - lane;
      unsigned d = (idx >= 0)
          ? __hip_atomic_load(&state[idx], __ATOMIC_ACQUIRE, __HIP_MEMORY_SCOPE_AGENT)
          : (2u << 30);
      unsigned st = d >> 30;
      unsigned long long m2 = __ballot(st == 2u);
      unsigned long long m0 = __ballot(st == 0u);
      int f2 = m2 ? ((int)__ffsll((long long)m2) - 1) : 64;
      int f0 = m0 ? ((int)__ffsll((long long)m0) - 1) : 64;
      if (f0 < f2) continue;
      int take = (lane < f2 || (lane == f2 && f2 < 64)) ? (int)(d & 0x3FFFFFFFu) : 0;
#pragma unroll
      for (int off = 1; off < 64; off <<= 1) take += __shfl_xor(take, off, 64);
      ex += take;
      if (f2 < 64) break;
      j -= 64;
    }
    if (lane == 0) {
      __hip_atomic_store(&state[bid], (2u << 30) | (unsigned)(ex + blocktotal),
                         __ATOMIC_RELEASE, __HIP_MEMORY_SCOPE_AGENT);
      sprefix = ex;
    }
  }
  __syncthreads();

  int e = sprefix + acc - tsum;
#pragma unroll
  for (int j = 0; j < 4; ++j) {
    int idx = base + j;
    if (idx < N) {
      offsets[idx] = e;
      int run = e;
#pragma unroll
      for (int k = 0; k < NPRIV; ++k) { suboff[(size_t)k * N + idx] = run; run += c[j][k]; }
      cursor[idx] = e;                // fallback-scatter cursor init
      e += v[j];
    }
  }
  if (bid == nb - 1 && threadIdx.x == 255) offsets[N] = total;
}

// ---------------- atomic-free scatter using precomputed ranks (2 edges/iter) ----
__global__ __launch_bounds__(256) void gat_scatter_rank(
    const int* __restrict__ ei, int E, int N,
    const int* __restrict__ suboff, const int* __restrict__ rank,
    int* __restrict__ scol)
{
  __shared__ int sh64;
  if (threadIdx.x == 0) sh64 = 1;
  __syncthreads();
  if (ei[2 * threadIdx.x + 1] != 0) sh64 = 0;
  __syncthreads();
  const int is64 = sh64;

  const int gid = (int)blockIdx.x * 256 + threadIdx.x;
  const int stride = gridDim.x * 256;
  const int npairs = (E + 1) >> 1;
  for (int p = gid; p < npairs; p += stride) {
    int r0, r1, c0v, c1v;
    const int i1ok = (2 * p + 1) < E;
    if (is64) {
      int4 rr = *(const int4*)(ei + 4 * (size_t)p);
      int2 ca = *(const int2*)(ei + 2 * (size_t)E + 4 * (size_t)p);
      int2 cb = *(const int2*)(ei + 2 * (size_t)E + 4 * (size_t)p + 2);
      r0 = rr.x; r1 = rr.z; c0v = ca.x; c1v = cb.x;
    } else {
      int2 rr = ((const int2*)ei)[p];
      r0 = rr.x; r1 = rr.y;
      c0v = ei[E + 2 * p];
      c1v = i1ok ? ei[E + 2 * p + 1] : 0;
    }
    int2 pr = ((const int2*)rank)[p];
    int k0 = (int)(((unsigned)pr.x) >> 28);
    int pos0 = suboff[(size_t)k0 * N + r0] + (pr.x & 0x0FFFFFFF);
    scol[pos0] = c0v;
    if (i1ok) {
      int k1 = (int)(((unsigned)pr.y) >> 28);
      int pos1 = suboff[(size_t)k1 * N + r1] + (pr.y & 0x0FFFFFFF);
      scol[pos1] = c1v;
    }
  }
}

// ---------------- fallback: atomic-cursor scatter (if ws too small) ----------
__global__ __launch_bounds__(256) void gat_scatter(
    const int* __restrict__ ei, int E, int N,
    int* __restrict__ cursor, int* __restrict__ scol)
{
  __shared__ int sh64;
  if (threadIdx.x == 0) sh64 = 1;
  __syncthreads();
  if (ei[2 * threadIdx.x + 1] != 0) sh64 = 0;
  __syncthreads();
  const int is64 = sh64;

  int i = blockIdx.x * 256 + threadIdx.x;
  const int stride = gridDim.x * 256;
  for (; i < E; i += stride) {
    int r, c;
    if (is64) { r = ei[2 * i]; c = ei[2 * (E + i)]; }
    else      { r = ei[i];     c = ei[E + i]; }
    int pos = atomicAdd(&cursor[r], 1);
    scol[pos] = c;
  }
}

// ---------------- per-row softmax + SpMM, one wave per row ----------------
// Self-loop analytic, masked to lane-group 0 (epilogue reduce sums groups).
// 4 edges/wave-iter; depth-2 gather pipeline (random-gather fabric ceiling).
__global__ __launch_bounds__(256) void gat_agg(
    const uint* __restrict__ hb, const float* __restrict__ s, const float* __restrict__ dv,
    const int* __restrict__ offsets, const int* __restrict__ scol,
    float* __restrict__ out, int N)
{
  int wid = (int)((blockIdx.x * 256 + threadIdx.x) >> 6);
  int lane = threadIdx.x & 63;
  if (wid >= N) return;
  const int g = lane >> 4;          // edge slot within quad
  const int t = lane & 15;          // dims 8t..8t+7
  const int head = t >> 1;
  const int beg = __builtin_amdgcn_readfirstlane(offsets[wid]);
  const int end = __builtin_amdgcn_readfirstlane(offsets[wid + 1]);
  const float sl = s[wid * 8 + head];

  const char* hbp = (const char*)hb;
  const char* dvp = (const char*)dv;
  const uint hoff = (uint)t * 16u;
  const uint doff = (uint)head * 4u;

  // self-loop contribution (group 0 only)
  float dls = *(const float*)(dvp + ((uint)wid * 32u + doff));
  uint4 hus = *(const uint4*)(hbp + ((uint)wid * 256u + hoff));
  float es = sl + dls;
  es = fmaxf(es, NEG_SLOPE * es);
  float ws = (g == 0) ? __expf(es) : 0.f;
  float z = ws;
  float a0 = ws * __uint_as_float(hus.x << 16);
  float a1 = ws * __uint_as_float(hus.x & 0xFFFF0000u);
  float a2 = ws * __uint_as_float(hus.y << 16);
  float a3 = ws * __uint_as_float(hus.y & 0xFFFF0000u);
  float a4 = ws * __uint_as_float(hus.z << 16);
  float a5 = ws * __uint_as_float(hus.z & 0xFFFF0000u);
  float a6 = ws * __uint_as_float(hus.w << 16);
  float a7 = ws * __uint_as_float(hus.w & 0xFFFF0000u);

  if (end > beg) {
    const int nq = (end - beg + 3) >> 2;
    const int lasti = end - 1;

    int iA = beg + g;       iA = iA < end ? iA : lasti;
    int iB = beg + 4 + g;   iB = iB < end ? iB : lasti;
    int iC = beg + 8 + g;   iC = iC < end ? iC : lasti;
    int cB = scol[iB];
    int cC = scol[iC];
    int cA = scol[iA];
    float dlA = *(const float*)(dvp + ((uint)cA * 32u + doff));
    uint4 huA = *(const uint4*)(hbp + ((uint)cA * 256u + hoff));
    float dlB = *(const float*)(dvp + ((uint)cB * 32u + doff));
    uint4 huB = *(const uint4*)(hbp + ((uint)cB * 256u + hoff));

    for (int j = 0; j < nq; ++j) {
      int iD = beg + 4 * (j + 3) + g; iD = iD < end ? iD : lasti;
      int cD = scol[iD];
      float dlC = *(const float*)(dvp + ((uint)cC * 32u + doff));
      uint4 huC = *(const uint4*)(hbp + ((uint)cC * 256u + hoff));

      float e = sl + dlA;
      e = fmaxf(e, NEG_SLOPE * e);
      float w = (beg + 4 * j + g < end) ? __expf(e) : 0.f;
      z += w;
      a0 = fmaf(w, __uint_as_float(huA.x << 16), a0);
      a1 = fmaf(w, __uint_as_float(huA.x & 0xFFFF0000u), a1);
      a2 = fmaf(w, __uint_as_float(huA.y << 16), a2);
      a3 = fmaf(w, __uint_as_float(huA.y & 0xFFFF0000u), a3);
      a4 = fmaf(w, __uint_as_float(huA.z << 16), a4);
      a5 = fmaf(w, __uint_as_float(huA.z & 0xFFFF0000u), a5);
      a6 = fmaf(w, __uint_as_float(huA.w << 16), a6);
      a7 = fmaf(w, __uint_as_float(huA.w & 0xFFFF0000u), a7);

      dlA = dlB; huA = huB;
      dlB = dlC; huB = huC;
      cC = cD;
    }
  }

  a0 += __shfl_xor(a0, 16, 64); a0 += __shfl_xor(a0, 32, 64);
  a1 += __shfl_xor(a1, 16, 64); a1 += __shfl_xor(a1, 32, 64);
  a2 += __shfl_xor(a2, 16, 64); a2 += __shfl_xor(a2, 32, 64);
  a3 += __shfl_xor(a3, 16, 64); a3 += __shfl_xor(a3, 32, 64);
  a4 += __shfl_xor(a4, 16, 64); a4 += __shfl_xor(a4, 32, 64);
  a5 += __shfl_xor(a5, 16, 64); a5 += __shfl_xor(a5, 32, 64);
  a6 += __shfl_xor(a6, 16, 64); a6 += __shfl_xor(a6, 32, 64);
  a7 += __shfl_xor(a7, 16, 64); a7 += __shfl_xor(a7, 32, 64);
  z  += __shfl_xor(z, 16, 64);  z  += __shfl_xor(z, 32, 64);

  float inv = 1.f / z;
  if (lane < 16) {
    float4* op = (float4*)(out + (size_t)wid * 128 + t * 8);
    op[0] = make_float4(a0 * inv, a1 * inv, a2 * inv, a3 * inv);
    op[1] = make_float4(a4 * inv, a5 * inv, a6 * inv, a7 * inv);
  }
}

extern "C" void kernel_launch(void* const* d_in, const int* in_sizes, int n_in,
                              void* d_out, int out_size, void* d_ws, size_t ws_size,
                              hipStream_t stream) {
  const float* x    = (const float*)d_in[0];
  const int*   ei   = (const int*)d_in[1];
  const float* W    = (const float*)d_in[2];
  const float* srcA = (const float*)d_in[3];
  const float* dstA = (const float*)d_in[4];
  float* out = (float*)d_out;
  const int N = in_sizes[0] / 128;
  const int E = in_sizes[1] / 2;

  auto need = [&](int npriv, int userank) -> size_t {
    size_t b = (size_t)N * 128 * 2;          // hbuf
    b += (size_t)N * 8 * 4 * 2;              // s, dv
    b += 36864;                              // wbf
    b += (size_t)npriv * N * 4;              // count8
    b += (size_t)(N + 1) * 4;                // offsets
    b += (size_t)npriv * N * 4;              // suboff
    b += (size_t)N * 4;                      // cursor
    b += 256 * 4 + 16;                       // state + ticket
    b += (size_t)E * 4;                      // scol
    if (userank) b += (size_t)(E + 1) * 4;   // rank (padded for pair store)
    return b;
  };
  int npriv = 8, userank = 1;
  if (need(8, 1) > ws_size) { npriv = 1; userank = 1; }
  if (need(1, 1) > ws_size) { npriv = 1; userank = 0; }

  ushort* hbuf = (ushort*)d_ws;                       // N*128 bf16
  float* s  = (float*)(hbuf + (size_t)N * 128);       // N*8
  float* dv = s + (size_t)N * 8;                      // N*8
  ushort* wbf = (ushort*)(dv + (size_t)N * 8);        // 36864 B
  int* count8  = (int*)((char*)wbf + 36864);          // npriv*N
  int* offsets = count8 + (size_t)npriv * N;          // N+1
  int* suboff  = offsets + (N + 1);                   // npriv*N
  int* cursor  = suboff + (size_t)npriv * N;          // N
  unsigned int* state = (unsigned int*)(cursor + N);  // 256
  int* ticket  = (int*)(state + 256);                 // 4 (padded)
  int* scol    = ticket + 4;                          // E
  int* rank    = scol + E;                            // E+1 (if userank)

  const int nchunks = (N + 63) / 64;
  const int nb = (N + 1023) / 1024;
  const int NG = 1536, NH = 1024;                     // 3:2 role split (R13)

  (void)hipMemsetAsync(count8, 0, (size_t)npriv * N * sizeof(int), stream);
  (void)hipMemsetAsync(state, 0, 256 * sizeof(int) + 16, stream);  // + ticket
  gat_prep_wbf<<<9, 256, 0, stream>>>(W, srcA, dstA, wbf);
  gat_gemm_hist<<<2560, 256, 0, stream>>>(x, wbf, hbuf, s, dv, N, nchunks, NG, NH,
                                          ei, E, count8, rank, userank);
  if (npriv == 8)
    gat_scan<8><<<nb, 256, 0, stream>>>(count8, N, nb, state, ticket, offsets,
                                        suboff, cursor, E);
  else
    gat_scan<1><<<nb, 256, 0, stream>>>(count8, N, nb, state, ticket, offsets,
                                        suboff, cursor, E);
  if (userank)
    gat_scatter_rank<<<2048, 256, 0, stream>>>(ei, E, N, suboff, rank, scol);
  else
    gat_scatter<<<2048, 256, 0, stream>>>(ei, E, N, cursor, scol);
  gat_agg<<<(N + 3) / 4, 256, 0, stream>>>((const uint*)hbuf, s, dv, offsets, scol, out, N);
}

// Round 17
// 201.231 us; speedup vs baseline: 1.0815x; 1.0523x over previous
//
#include <hip/hip_runtime.h>
#include <hip/hip_bf16.h>
#include <math.h>

#define NEG_SLOPE 0.2f

typedef __attribute__((ext_vector_type(8))) short short8v;
typedef __attribute__((ext_vector_type(4))) float f32x4;

// ---------------- prep: zero count8/state/ticket + pack B fragments ----------
// Single dispatch: zeroing strided across 2048 blocks; wbf built by first
// 2304 threads. One launch instead of memset+memset+prep (launch gaps cost
// ~4 us each at this scale — measured R13 vs R16).
__global__ __launch_bounds__(256) void gat_prep(
    const float* __restrict__ W, const float* __restrict__ srcA,
    const float* __restrict__ dstA, ushort* __restrict__ wbf,
    int* __restrict__ count8, int cn,
    unsigned int* __restrict__ state, int* __restrict__ ticket)
{
  int gtid = blockIdx.x * 256 + threadIdx.x;
  for (int i = gtid; i < cn; i += gridDim.x * 256)
    count8[i] = 0;
  if (gtid < 256) state[gtid] = 0;
  if (gtid == 0) *ticket = 0;

  if (gtid >= 36 * 64) return;
  int frag = gtid >> 6, lane = gtid & 63;
  int nt = frag >> 2, ks = frag & 3;
  int kbase = ks * 32 + (lane >> 4) * 8;
  ushort v[8];
  if (nt < 8) {
    int r = nt * 16 + (lane & 15);   // output col n -> W row
#pragma unroll
    for (int j = 0; j < 8; ++j)
      v[j] = __bfloat16_as_ushort(__float2bfloat16(W[(size_t)r * 128 + kbase + j]));
  } else {
    int n = lane & 15;
    int hd = n & 7;
    const float* av = (n < 8) ? srcA : dstA;
#pragma unroll
    for (int j = 0; j < 8; ++j) {
      float acc = 0.f;
      int k = kbase + j;
      for (int d = 0; d < 16; ++d)
        acc += W[(size_t)(hd * 16 + d) * 128 + k] * av[hd * 16 + d];
      v[j] = __bfloat16_as_ushort(__float2bfloat16(acc));
    }
  }
  ushort* dst = wbf + ((size_t)frag * 64 + lane) * 8;
#pragma unroll
  for (int j = 0; j < 8; ++j) dst[j] = v[j];
}

// ---------------- fused: MFMA GEMM (3/5 of blocks) + privatized histogram ----
__global__ __launch_bounds__(256, 2) void gat_gemm_hist(
    const float* __restrict__ x, const ushort* __restrict__ wbf,
    ushort* __restrict__ hb, float* __restrict__ s, float* __restrict__ dv,
    int N, int nchunks, int NG, int NH,
    const int* __restrict__ ei, int E, int* __restrict__ count8,
    int* __restrict__ rank, int userank)
{
  const int q = (int)blockIdx.x / 5;
  const int r5 = (int)blockIdx.x % 5;
  if (r5 < 3) {
    // ---- GEMM block (q*3 + r5) of NG; b[36] loaded once, chunk loop ----
    const int gemmId = q * 3 + r5;
    const int wave = threadIdx.x >> 6, lane = threadIdx.x & 63;
    const int lrow = lane & 15, lkg = lane >> 4;

    short8v b[36];
    const short8v* wv = (const short8v*)wbf;
#pragma unroll
    for (int f = 0; f < 36; ++f) b[f] = wv[(size_t)f * 64 + lane];

    for (int chunk = gemmId; chunk < nchunks; chunk += NG) {
      const int r0 = chunk * 64 + wave * 16;
      int arow = r0 + lrow; if (arow > N - 1) arow = N - 1;
      const float* xr = x + (size_t)arow * 128 + lkg * 8;

      f32x4 acc[9];
#pragma unroll
      for (int t = 0; t < 9; ++t) acc[t] = (f32x4){0.f, 0.f, 0.f, 0.f};

#pragma unroll
      for (int ks = 0; ks < 4; ++ks) {
        float4 x0 = *(const float4*)(xr + ks * 32);
        float4 x1 = *(const float4*)(xr + ks * 32 + 4);
        short8v a;
        a[0] = (short)__bfloat16_as_ushort(__float2bfloat16(x0.x));
        a[1] = (short)__bfloat16_as_ushort(__float2bfloat16(x0.y));
        a[2] = (short)__bfloat16_as_ushort(__float2bfloat16(x0.z));
        a[3] = (short)__bfloat16_as_ushort(__float2bfloat16(x0.w));
        a[4] = (short)__bfloat16_as_ushort(__float2bfloat16(x1.x));
        a[5] = (short)__bfloat16_as_ushort(__float2bfloat16(x1.y));
        a[6] = (short)__bfloat16_as_ushort(__float2bfloat16(x1.z));
        a[7] = (short)__bfloat16_as_ushort(__float2bfloat16(x1.w));
#pragma unroll
        for (int t = 0; t < 9; ++t)
          acc[t] = __builtin_amdgcn_mfma_f32_16x16x32_bf16(a, b[t * 4 + ks], acc[t], 0, 0, 0);
      }

      const int rbase = r0 + lkg * 4;  // C/D: row = (lane>>4)*4 + reg, col = lane&15
#pragma unroll
      for (int t = 0; t < 8; ++t) {
#pragma unroll
        for (int r = 0; r < 4; ++r) {
          int row = rbase + r;
          if (row < N)
            hb[(size_t)row * 128 + t * 16 + lrow] =
                __bfloat16_as_ushort(__float2bfloat16(acc[t][r]));
        }
      }
#pragma unroll
      for (int r = 0; r < 4; ++r) {
        int row = rbase + r;
        if (row < N) {
          if (lrow < 8) s[(size_t)row * 8 + lrow] = acc[8][r];
          else          dv[(size_t)row * 8 + (lrow - 8)] = acc[8][r];
        }
      }
    }
  } else {
    // ---- hist block (q*2 + r5-3) of NH; 2 edges/iter; copy k = blockIdx&7 ----
    __shared__ int sh64;
    if (threadIdx.x == 0) sh64 = 1;
    __syncthreads();
    if (ei[2 * threadIdx.x + 1] != 0) sh64 = 0;  // int32 layout -> odd word != 0
    __syncthreads();
    const int is64 = sh64;
    const int k = (int)(blockIdx.x & 7u);
    int* cnt = count8 + (size_t)k * N;

    const int histId = q * 2 + (r5 - 3);
    const int npairs = (E + 1) >> 1;
    const int pstride = NH * 256;
    for (int p = histId * 256 + threadIdx.x; p < npairs; p += pstride) {
      int r0, r1;
      const int i1ok = (2 * p + 1) < E;
      if (is64) {
        int4 rr = *(const int4*)(ei + 4 * (size_t)p);
        r0 = rr.x; r1 = rr.z;
      } else {
        int2 rr = ((const int2*)ei)[p];
        r0 = rr.x; r1 = rr.y;
      }
      int old0 = atomicAdd(&cnt[r0], 1);
      int old1 = i1ok ? atomicAdd(&cnt[r1], 1) : 0;
      if (userank) {
        if (i1ok) ((int2*)rank)[p] = make_int2(old0 | (k << 28), old1 | (k << 28));
        else      rank[2 * p] = old0 | (k << 28);
      }
    }
  }
}

// ---------------- decoupled-lookback scan over npriv copies (E-only) ----------
template<int NPRIV>
__global__ __launch_bounds__(256) void gat_scan(
    const int* __restrict__ count8, int N, int nb,
    unsigned int* __restrict__ state, int* __restrict__ ticket,
    int* __restrict__ offsets, int* __restrict__ suboff,
    int* __restrict__ cursor, int total)
{
  __shared__ int sbid;
  __shared__ int sm[256];
  __shared__ int sprefix;
  if (threadIdx.x == 0) sbid = atomicAdd(ticket, 1);
  __syncthreads();
  const int bid = sbid;
  const int base = bid * 1024 + threadIdx.x * 4;

  int c[4][NPRIV];
  int v[4];
  int tsum = 0;
#pragma unroll
  for (int j = 0; j < 4; ++j) {
    int idx = base + j;
    int cs = 0;
#pragma unroll
    for (int k = 0; k < NPRIV; ++k) {
      int cv = (idx < N) ? count8[(size_t)k * N + idx] : 0;
      c[j][k] = cv; cs += cv;
    }
    v[j] = (idx < N) ? cs : 0;       // no self-loop slot (agg handles self)
    tsum += v[j];
  }

  sm[threadIdx.x] = tsum;
  __syncthreads();
  int acc = tsum;
  for (int off = 1; off < 256; off <<= 1) {
    int other = (threadIdx.x >= off) ? sm[threadIdx.x - off] : 0;
    __syncthreads();
    acc += other;
    sm[threadIdx.x] = acc;
    __syncthreads();
  }
  const int blocktotal = sm[255];

  if (threadIdx.x == 0)
    __hip_atomic_store(&state[bid], (1u << 30) | (unsigned)blocktotal,
                       __ATOMIC_RELEASE, __HIP_MEMORY_SCOPE_AGENT);
  if (threadIdx.x < 64) {
    const int lane = threadIdx.x;
    int ex = 0;
    int j = bid - 1;
    while (j >= 0) {
      int idx = j - lane;
      unsigned d = (idx >= 0)
          ? __hip_atomic_load(&state[idx], __ATOMIC_ACQUIRE, __HIP_MEMORY_SCOPE_AGENT)
          : (2u << 30);
      unsigned st = d >> 30;
      unsigned long long m2 = __ballot(st == 2u);
      unsigned long long m0 = __ballot(st == 0u);
      int f2 = m2 ? ((int)__ffsll((long long)m2) - 1) : 64;
      int f0 = m0 ? ((int)__ffsll((long long)m0) - 1) : 64;
      if (f0 < f2) continue;
      int take = (lane < f2 || (lane == f2 && f2 < 64)) ? (int)(d & 0x3FFFFFFFu) : 0;
#pragma unroll
      for (int off = 1; off < 64; off <<= 1) take += __shfl_xor(take, off, 64);
      ex += take;
      if (f2 < 64) break;
      j -= 64;
    }
    if (lane == 0) {
      __hip_atomic_store(&state[bid], (2u << 30) | (unsigned)(ex + blocktotal),
                         __ATOMIC_RELEASE, __HIP_MEMORY_SCOPE_AGENT);
      sprefix = ex;
    }
  }
  __syncthreads();

  int e = sprefix + acc - tsum;
#pragma unroll
  for (int j = 0; j < 4; ++j) {
    int idx = base + j;
    if (idx < N) {
      offsets[idx] = e;
      int run = e;
#pragma unroll
      for (int k = 0; k < NPRIV; ++k) { suboff[(size_t)k * N + idx] = run; run += c[j][k]; }
      cursor[idx] = e;                // fallback-scatter cursor init
      e += v[j];
    }
  }
  if (bid == nb - 1 && threadIdx.x == 255) offsets[N] = total;
}

// ---------------- atomic-free scatter using precomputed ranks (2 edges/iter) ----
__global__ __launch_bounds__(256) void gat_scatter_rank(
    const int* __restrict__ ei, int E, int N,
    const int* __restrict__ suboff, const int* __restrict__ rank,
    int* __restrict__ scol)
{
  __shared__ int sh64;
  if (threadIdx.x == 0) sh64 = 1;
  __syncthreads();
  if (ei[2 * threadIdx.x + 1] != 0) sh64 = 0;
  __syncthreads();
  const int is64 = sh64;

  const int gid = (int)blockIdx.x * 256 + threadIdx.x;
  const int stride = gridDim.x * 256;
  const int npairs = (E + 1) >> 1;
  for (int p = gid; p < npairs; p += stride) {
    int r0, r1, c0v, c1v;
    const int i1ok = (2 * p + 1) < E;
    if (is64) {
      int4 rr = *(const int4*)(ei + 4 * (size_t)p);
      int2 ca = *(const int2*)(ei + 2 * (size_t)E + 4 * (size_t)p);
      int2 cb = *(const int2*)(ei + 2 * (size_t)E + 4 * (size_t)p + 2);
      r0 = rr.x; r1 = rr.z; c0v = ca.x; c1v = cb.x;
    } else {
      int2 rr = ((const int2*)ei)[p];
      r0 = rr.x; r1 = rr.y;
      c0v = ei[E + 2 * p];
      c1v = i1ok ? ei[E + 2 * p + 1] : 0;
    }
    int2 pr = ((const int2*)rank)[p];
    int k0 = (int)(((unsigned)pr.x) >> 28);
    int pos0 = suboff[(size_t)k0 * N + r0] + (pr.x & 0x0FFFFFFF);
    scol[pos0] = c0v;
    if (i1ok) {
      int k1 = (int)(((unsigned)pr.y) >> 28);
      int pos1 = suboff[(size_t)k1 * N + r1] + (pr.y & 0x0FFFFFFF);
      scol[pos1] = c1v;
    }
  }
}

// ---------------- fallback: atomic-cursor scatter (if ws too small) ----------
__global__ __launch_bounds__(256) void gat_scatter(
    const int* __restrict__ ei, int E, int N,
    int* __restrict__ cursor, int* __restrict__ scol)
{
  __shared__ int sh64;
  if (threadIdx.x == 0) sh64 = 1;
  __syncthreads();
  if (ei[2 * threadIdx.x + 1] != 0) sh64 = 0;
  __syncthreads();
  const int is64 = sh64;

  int i = blockIdx.x * 256 + threadIdx.x;
  const int stride = gridDim.x * 256;
  for (; i < E; i += stride) {
    int r, c;
    if (is64) { r = ei[2 * i]; c = ei[2 * (E + i)]; }
    else      { r = ei[i];     c = ei[E + i]; }
    int pos = atomicAdd(&cursor[r], 1);
    scol[pos] = c;
  }
}

// ---------------- per-row softmax + SpMM, one wave per row ----------------
// Self-loop analytic, masked to lane-group 0 (epilogue reduce sums groups).
// 4 edges/wave-iter; depth-2 gather pipeline (random-gather fabric ceiling).
__global__ __launch_bounds__(256) void gat_agg(
    const uint* __restrict__ hb, const float* __restrict__ s, const float* __restrict__ dv,
    const int* __restrict__ offsets, const int* __restrict__ scol,
    float* __restrict__ out, int N)
{
  int wid = (int)((blockIdx.x * 256 + threadIdx.x) >> 6);
  int lane = threadIdx.x & 63;
  if (wid >= N) return;
  const int g = lane >> 4;          // edge slot within quad
  const int t = lane & 15;          // dims 8t..8t+7
  const int head = t >> 1;
  const int beg = __builtin_amdgcn_readfirstlane(offsets[wid]);
  const int end = __builtin_amdgcn_readfirstlane(offsets[wid + 1]);
  const float sl = s[wid * 8 + head];

  const char* hbp = (const char*)hb;
  const char* dvp = (const char*)dv;
  const uint hoff = (uint)t * 16u;
  const uint doff = (uint)head * 4u;

  // self-loop contribution (group 0 only)
  float dls = *(const float*)(dvp + ((uint)wid * 32u + doff));
  uint4 hus = *(const uint4*)(hbp + ((uint)wid * 256u + hoff));
  float es = sl + dls;
  es = fmaxf(es, NEG_SLOPE * es);
  float ws = (g == 0) ? __expf(es) : 0.f;
  float z = ws;
  float a0 = ws * __uint_as_float(hus.x << 16);
  float a1 = ws * __uint_as_float(hus.x & 0xFFFF0000u);
  float a2 = ws * __uint_as_float(hus.y << 16);
  float a3 = ws * __uint_as_float(hus.y & 0xFFFF0000u);
  float a4 = ws * __uint_as_float(hus.z << 16);
  float a5 = ws * __uint_as_float(hus.z & 0xFFFF0000u);
  float a6 = ws * __uint_as_float(hus.w << 16);
  float a7 = ws * __uint_as_float(hus.w & 0xFFFF0000u);

  if (end > beg) {
    const int nq = (end - beg + 3) >> 2;
    const int lasti = end - 1;

    int iA = beg + g;       iA = iA < end ? iA : lasti;
    int iB = beg + 4 + g;   iB = iB < end ? iB : lasti;
    int iC = beg + 8 + g;   iC = iC < end ? iC : lasti;
    int cB = scol[iB];
    int cC = scol[iC];
    int cA = scol[iA];
    float dlA = *(const float*)(dvp + ((uint)cA * 32u + doff));
    uint4 huA = *(const uint4*)(hbp + ((uint)cA * 256u + hoff));
    float dlB = *(const float*)(dvp + ((uint)cB * 32u + doff));
    uint4 huB = *(const uint4*)(hbp + ((uint)cB * 256u + hoff));

    for (int j = 0; j < nq; ++j) {
      int iD = beg + 4 * (j + 3) + g; iD = iD < end ? iD : lasti;
      int cD = scol[iD];
      float dlC = *(const float*)(dvp + ((uint)cC * 32u + doff));
      uint4 huC = *(const uint4*)(hbp + ((uint)cC * 256u + hoff));

      float e = sl + dlA;
      e = fmaxf(e, NEG_SLOPE * e);
      float w = (beg + 4 * j + g < end) ? __expf(e) : 0.f;
      z += w;
      a0 = fmaf(w, __uint_as_float(huA.x << 16), a0);
      a1 = fmaf(w, __uint_as_float(huA.x & 0xFFFF0000u), a1);
      a2 = fmaf(w, __uint_as_float(huA.y << 16), a2);
      a3 = fmaf(w, __uint_as_float(huA.y & 0xFFFF0000u), a3);
      a4 = fmaf(w, __uint_as_float(huA.z << 16), a4);
      a5 = fmaf(w, __uint_as_float(huA.z & 0xFFFF0000u), a5);
      a6 = fmaf(w, __uint_as_float(huA.w << 16), a6);
      a7 = fmaf(w, __uint_as_float(huA.w & 0xFFFF0000u), a7);

      dlA = dlB; huA = huB;
      dlB = dlC; huB = huC;
      cC = cD;
    }
  }

  a0 += __shfl_xor(a0, 16, 64); a0 += __shfl_xor(a0, 32, 64);
  a1 += __shfl_xor(a1, 16, 64); a1 += __shfl_xor(a1, 32, 64);
  a2 += __shfl_xor(a2, 16, 64); a2 += __shfl_xor(a2, 32, 64);
  a3 += __shfl_xor(a3, 16, 64); a3 += __shfl_xor(a3, 32, 64);
  a4 += __shfl_xor(a4, 16, 64); a4 += __shfl_xor(a4, 32, 64);
  a5 += __shfl_xor(a5, 16, 64); a5 += __shfl_xor(a5, 32, 64);
  a6 += __shfl_xor(a6, 16, 64); a6 += __shfl_xor(a6, 32, 64);
  a7 += __shfl_xor(a7, 16, 64); a7 += __shfl_xor(a7, 32, 64);
  z  += __shfl_xor(z, 16, 64);  z  += __shfl_xor(z, 32, 64);

  float inv = 1.f / z;
  if (lane < 16) {
    float4* op = (float4*)(out + (size_t)wid * 128 + t * 8);
    op[0] = make_float4(a0 * inv, a1 * inv, a2 * inv, a3 * inv);
    op[1] = make_float4(a4 * inv, a5 * inv, a6 * inv, a7 * inv);
  }
}

extern "C" void kernel_launch(void* const* d_in, const int* in_sizes, int n_in,
                              void* d_out, int out_size, void* d_ws, size_t ws_size,
                              hipStream_t stream) {
  const float* x    = (const float*)d_in[0];
  const int*   ei   = (const int*)d_in[1];
  const float* W    = (const float*)d_in[2];
  const float* srcA = (const float*)d_in[3];
  const float* dstA = (const float*)d_in[4];
  float* out = (float*)d_out;
  const int N = in_sizes[0] / 128;
  const int E = in_sizes[1] / 2;

  auto need = [&](int npriv, int userank) -> size_t {
    size_t b = (size_t)N * 128 * 2;          // hbuf
    b += (size_t)N * 8 * 4 * 2;              // s, dv
    b += 36864;                              // wbf
    b += (size_t)npriv * N * 4;              // count8
    b += (size_t)(N + 1) * 4;                // offsets
    b += (size_t)npriv * N * 4;              // suboff
    b += (size_t)N * 4;                      // cursor
    b += 256 * 4 + 16;                       // state + ticket
    b += (size_t)E * 4;                      // scol
    if (userank) b += (size_t)(E + 1) * 4;   // rank (padded for pair store)
    return b;
  };
  int npriv = 8, userank = 1;
  if (need(8, 1) > ws_size) { npriv = 1; userank = 1; }
  if (need(1, 1) > ws_size) { npriv = 1; userank = 0; }

  ushort* hbuf = (ushort*)d_ws;                       // N*128 bf16
  float* s  = (float*)(hbuf + (size_t)N * 128);       // N*8
  float* dv = s + (size_t)N * 8;                      // N*8
  ushort* wbf = (ushort*)(dv + (size_t)N * 8);        // 36864 B
  int* count8  = (int*)((char*)wbf + 36864);          // npriv*N
  int* offsets = count8 + (size_t)npriv * N;          // N+1
  int* suboff  = offsets + (N + 1);                   // npriv*N
  int* cursor  = suboff + (size_t)npriv * N;          // N
  unsigned int* state = (unsigned int*)(cursor + N);  // 256
  int* ticket  = (int*)(state + 256);                 // 4 (padded)
  int* scol    = ticket + 4;                          // E
  int* rank    = scol + E;                            // E+1 (if userank)

  const int nchunks = (N + 63) / 64;
  const int nb = (N + 1023) / 1024;
  const int NG = 1536, NH = 1024;                     // 3:2 role split (R13)

  gat_prep<<<2048, 256, 0, stream>>>(W, srcA, dstA, wbf, count8, npriv * N, state, ticket);
  gat_gemm_hist<<<2560, 256, 0, stream>>>(x, wbf, hbuf, s, dv, N, nchunks, NG, NH,
                                          ei, E, count8, rank, userank);
  if (npriv == 8)
    gat_scan<8><<<nb, 256, 0, stream>>>(count8, N, nb, state, ticket, offsets,
                                        suboff, cursor, E);
  else
    gat_scan<1><<<nb, 256, 0, stream>>>(count8, N, nb, state, ticket, offsets,
                                        suboff, cursor, E);
  if (userank)
    gat_scatter_rank<<<2048, 256, 0, stream>>>(ei, E, N, suboff, rank, scol);
  else
    gat_scatter<<<2048, 256, 0, stream>>>(ei, E, N, cursor, scol);
  gat_agg<<<(N + 3) / 4, 256, 0, stream>>>((const uint*)hbuf, s, dv, offsets, scol, out, N);
}